// Round 4
// baseline (339.852 us; speedup 1.0000x reference)
//
#include <hip/hip_runtime.h>

// Fused attention prefill, bf16 MFMA pipeline.
// ws layout (ushort units, 1M = 1024*1024):
//   xb 0..4M | wqkvb 4M..10M | wob 10M..14M | qkvb 14M..20M | qb 20M..24M
//   kb 24M..25M | vt 25M..26M | yb 26M..30M   => 60 MB total.

typedef __attribute__((ext_vector_type(8))) __bf16 bf16x8;
typedef __attribute__((ext_vector_type(4))) float f32x4;

#define S_LEN 2048
#define DIMN  2048
#define NH    32
#define NKV   8
#define HD    64
#define QKVF  3072

__device__ __forceinline__ ushort f2bf(float f) {
  union { float f; unsigned u; } v; v.f = f;
  unsigned r = v.u + 0x7fffu + ((v.u >> 16) & 1u);
  return (ushort)(r >> 16);
}
__device__ __forceinline__ ushort f2bf_rz(float f) {
  union { float f; unsigned u; } v; v.f = f;
  return (ushort)(v.u >> 16);
}
__device__ __forceinline__ float bf2f(ushort u) {
  union { unsigned u; float f; } v; v.u = ((unsigned)u) << 16;
  return v.f;
}
__device__ __forceinline__ void gld_lds16(const void* g, void* l) {
  __builtin_amdgcn_global_load_lds(
      (const __attribute__((address_space(1))) unsigned int*)g,
      (__attribute__((address_space(3))) unsigned int*)l, 16, 0, 0);
}

// ---------------- f32 -> bf16 conversion (x, [wq;wk;wv], wo) ----------------
__global__ __launch_bounds__(256) void convert_all(
    const float* __restrict__ x, const float* __restrict__ wq,
    const float* __restrict__ wk, const float* __restrict__ wv,
    const float* __restrict__ wo, ushort* __restrict__ xb,
    ushort* __restrict__ wqkvb, ushort* __restrict__ wob) {
  const size_t NX = 4u * 1024 * 1024;
  const size_t NK = 1024 * 1024;
  size_t idx = ((size_t)blockIdx.x * 256 + threadIdx.x) * 4;
  const float* src; ushort* dst;
  if (idx < NX)                { src = x  + idx;                  dst = xb + idx; }
  else if (idx < 2 * NX)       { src = wq + (idx - NX);           dst = wqkvb + (idx - NX); }
  else if (idx < 2 * NX + NK)  { src = wk + (idx - 2 * NX);       dst = wqkvb + NX + (idx - 2 * NX); }
  else if (idx < 2 * NX + 2*NK){ src = wv + (idx - 2 * NX - NK);  dst = wqkvb + NX + NK + (idx - 2 * NX - NK); }
  else                         { src = wo + (idx - 2 * NX - 2*NK);dst = wob + (idx - 2 * NX - 2 * NK); }
  float4 v = *(const float4*)src;
  ushort4 o; o.x = f2bf(v.x); o.y = f2bf(v.y); o.z = f2bf(v.z); o.w = f2bf(v.w);
  *(ushort4*)dst = o;
}

// ---------------- GEMM (m97 structure): global_load_lds width-16, LDB=64 ----
template <int OUT_BF16>
__global__ __launch_bounds__(256) void gemm_bt(
    const ushort* __restrict__ A, const ushort* __restrict__ B,
    void* __restrict__ Cv, int M, int N, int K) {
  __shared__ __align__(16) ushort As[128 * 64];
  __shared__ __align__(16) ushort Bs[128 * 64];
  const int n0 = blockIdx.x * 128, m0 = blockIdx.y * 128;
  const int t = threadIdx.x;
  const int lane = t & 63, wave = t >> 6;
  const int wm = (wave >> 1) * 64, wn = (wave & 1) * 64;
  const int col = lane & 15, quad = lane >> 4;
  const int srow = wave * 32 + (lane >> 3);
  const int scol = (lane & 7) * 8;
  f32x4 acc[4][4] = {};
  for (int kk = 0; kk < K; kk += 64) {
    __syncthreads();
#pragma unroll
    for (int c = 0; c < 4; ++c) {
      int row = srow + c * 8;
      gld_lds16(&A[(size_t)(m0 + row) * K + kk + scol], &As[(wave * 32 + c * 8) * 64]);
      gld_lds16(&B[(size_t)(n0 + row) * K + kk + scol], &Bs[(wave * 32 + c * 8) * 64]);
    }
    __syncthreads();
#pragma unroll
    for (int kc = 0; kc < 64; kc += 32) {
      bf16x8 af[4], bfr[4];
#pragma unroll
      for (int i = 0; i < 4; ++i)
        af[i] = *(const bf16x8*)&As[(wm + i * 16 + col) * 64 + kc + quad * 8];
#pragma unroll
      for (int j = 0; j < 4; ++j)
        bfr[j] = *(const bf16x8*)&Bs[(wn + j * 16 + col) * 64 + kc + quad * 8];
#pragma unroll
      for (int i = 0; i < 4; ++i)
#pragma unroll
        for (int j = 0; j < 4; ++j)
          acc[i][j] = __builtin_amdgcn_mfma_f32_16x16x32_bf16(af[i], bfr[j], acc[i][j], 0, 0, 0);
    }
  }
#pragma unroll
  for (int i = 0; i < 4; ++i)
#pragma unroll
    for (int r = 0; r < 4; ++r) {
      int m = m0 + wm + i * 16 + quad * 4 + r;
      if (OUT_BF16) {
        ushort* C = (ushort*)Cv;
#pragma unroll
        for (int j = 0; j < 4; ++j)
          C[(size_t)m * N + n0 + wn + j * 16 + col] = f2bf(acc[i][j][r]);
      } else {
        float* C = (float*)Cv;
#pragma unroll
        for (int j = 0; j < 4; ++j)
          C[(size_t)m * N + n0 + wn + j * 16 + col] = acc[i][j][r];
      }
    }
}

// ---------------- RoPE + layout, coalesced ----------------------------------
// grid (48, 8): hh<32 -> q head, hh<40 -> k head, else v head (LDS transpose).
__global__ __launch_bounds__(256) void rope_layout(
    const ushort* __restrict__ qkv, const float* __restrict__ fc,
    const float* __restrict__ fs, ushort* __restrict__ qb,
    ushort* __restrict__ kb, ushort* __restrict__ vt) {
  __shared__ ushort T[64][72];
  const int hh = blockIdx.x;
  const int s0 = blockIdx.y * 256;
  const int t = threadIdx.x;
  if (hh < 40) {
    const int srcoff = (hh < 32) ? hh * 64 : 2048 + (hh - 32) * 64;
    ushort* dst = (hh < 32) ? qb + (size_t)hh * S_LEN * 64
                            : kb + (size_t)(hh - 32) * S_LEN * 64;
    const int sr = t >> 4, dc = (t & 15) * 4, i0 = (t & 15) * 2;
#pragma unroll 4
    for (int pass = 0; pass < 16; ++pass) {
      int s = s0 + pass * 16 + sr;
      ushort4 vv = *(const ushort4*)&qkv[(size_t)s * QKVF + srcoff + dc];
      float2 cc = *(const float2*)&fc[s * 32 + i0];
      float2 ss = *(const float2*)&fs[s * 32 + i0];
      float xr0 = bf2f(vv.x), xi0 = bf2f(vv.y), xr1 = bf2f(vv.z), xi1 = bf2f(vv.w);
      ushort4 ov;
      ov.x = f2bf(xr0 * cc.x - xi0 * ss.x); ov.y = f2bf(xr0 * ss.x + xi0 * cc.x);
      ov.z = f2bf(xr1 * cc.y - xi1 * ss.y); ov.w = f2bf(xr1 * ss.y + xi1 * cc.y);
      *(ushort4*)&dst[(size_t)s * 64 + dc] = ov;
    }
  } else {
    const int vh = hh - 40;
    for (int sub = 0; sub < 4; ++sub) {
      int sb = s0 + sub * 64;
      int sr = t >> 2, dc = (t & 3) * 16;
      ushort tmp[16];
      *(int4*)&tmp[0] = *(const int4*)&qkv[(size_t)(sb + sr) * QKVF + 2560 + vh * 64 + dc];
      *(int4*)&tmp[8] = *(const int4*)&qkv[(size_t)(sb + sr) * QKVF + 2560 + vh * 64 + dc + 8];
      __syncthreads();  // WAR vs previous sub's reads
#pragma unroll
      for (int k = 0; k < 16; ++k) T[dc + k][sr] = tmp[k];
      __syncthreads();
      int d = t >> 2, sc2 = (t & 3) * 16;
      int4 w0 = *(const int4*)&T[d][sc2];
      int4 w1 = *(const int4*)&T[d][sc2 + 8];
      *(int4*)&vt[((size_t)vh * 64 + d) * S_LEN + sb + sc2] = w0;
      *(int4*)&vt[((size_t)vh * 64 + d) * S_LEN + sb + sc2 + 8] = w1;
    }
  }
}

// ---------------- Flash attention v4: balanced strip pairs ------------------
// 16-row strips; wave processes strips (127-p) then (p): 33-34 tiles per wave,
// perfectly balanced. No barriers, P parity-double-buffered, K prefetch 1 ahead.
struct K8 { bf16x8 f[8]; };

__global__ __launch_bounds__(64) void attn(
    const ushort* __restrict__ qbg, const ushort* __restrict__ kbg,
    const ushort* __restrict__ vtg, ushort* __restrict__ yb) {
  __shared__ __align__(16) ushort Ps[2][16][72];
  const int h = blockIdx.x;
  const int p = blockIdx.y;
  const int kvh = h >> 2;
  const int lane = threadIdx.x;
  const int col = lane & 15, quad = lane >> 4;
  const ushort* qh = qbg + (size_t)h * S_LEN * HD;
  const ushort* kh = kbg + (size_t)kvh * S_LEN * HD;
  const ushort* vh = vtg + (size_t)kvh * HD * S_LEN;
  const float CLOG = 0.18033688011112042f;  // (1/8)*log2(e)

  auto run_strip = [&](int sX) {
    const int q0 = sX * 16;
    const int nt = (sX >> 2) + 1;
    bf16x8 qf[2];
    qf[0] = *(const bf16x8*)&qh[(size_t)(q0 + col) * HD + quad * 8];
    qf[1] = *(const bf16x8*)&qh[(size_t)(q0 + col) * HD + 32 + quad * 8];
    float l[4] = {};
    f32x4 o[4] = {};
    K8 kb0, kb1;
    auto loadK = [&](int t0, K8& k) {
#pragma unroll
      for (int j = 0; j < 4; ++j)
#pragma unroll
        for (int c = 0; c < 2; ++c)
          k.f[j * 2 + c] = *(const bf16x8*)&kh[(size_t)(t0 + j * 16 + col) * HD + c * 32 + quad * 8];
    };
    auto body = [&](int it, K8& cur, K8& nxt) {
      const int t0 = it * 64;
      const int pb = it & 1;
      f32x4 sc[4] = {};
#pragma unroll
      for (int j = 0; j < 4; ++j) {
        sc[j] = __builtin_amdgcn_mfma_f32_16x16x32_bf16(qf[0], cur.f[j * 2], sc[j], 0, 0, 0);
        sc[j] = __builtin_amdgcn_mfma_f32_16x16x32_bf16(qf[1], cur.f[j * 2 + 1], sc[j], 0, 0, 0);
      }
      if (it + 1 < nt) loadK(t0 + 64, nxt);
      bf16x8 vf[8];
#pragma unroll
      for (int db = 0; db < 4; ++db)
#pragma unroll
        for (int c = 0; c < 2; ++c)
          vf[db * 2 + c] = *(const bf16x8*)&vh[(size_t)(db * 16 + col) * S_LEN + t0 + c * 32 + quad * 8];
      const bool masked = (it == nt - 1);
#pragma unroll
      for (int r = 0; r < 4; ++r) {
        const int rowq = q0 + quad * 4 + r;
        float pr[4];
#pragma unroll
        for (int j = 0; j < 4; ++j) {
          float e = __builtin_amdgcn_exp2f(sc[j][r] * CLOG);
          if (masked) e = (t0 + j * 16 + col > rowq) ? 0.f : e;
          pr[j] = e;
        }
        l[r] += (pr[0] + pr[1]) + (pr[2] + pr[3]);
        const int prow = quad * 4 + r;
        Ps[pb][prow][col]      = f2bf_rz(pr[0]);
        Ps[pb][prow][16 + col] = f2bf_rz(pr[1]);
        Ps[pb][prow][32 + col] = f2bf_rz(pr[2]);
        Ps[pb][prow][48 + col] = f2bf_rz(pr[3]);
      }
      bf16x8 pf0 = *(const bf16x8*)&Ps[pb][col][quad * 8];
      bf16x8 pf1 = *(const bf16x8*)&Ps[pb][col][32 + quad * 8];
#pragma unroll
      for (int db = 0; db < 4; ++db) {
        o[db] = __builtin_amdgcn_mfma_f32_16x16x32_bf16(pf0, vf[db * 2], o[db], 0, 0, 0);
        o[db] = __builtin_amdgcn_mfma_f32_16x16x32_bf16(pf1, vf[db * 2 + 1], o[db], 0, 0, 0);
      }
    };
    loadK(0, kb0);
    int it = 0;
    while (true) {
      body(it, kb0, kb1);
      if (++it == nt) break;
      body(it, kb1, kb0);
      if (++it == nt) break;
    }
#pragma unroll
    for (int r = 0; r < 4; ++r) {
      float ls = l[r];
      ls += __shfl_xor(ls, 1);
      ls += __shfl_xor(ls, 2);
      ls += __shfl_xor(ls, 4);
      ls += __shfl_xor(ls, 8);
      float inv = 1.0f / ls;
      int rowq = q0 + quad * 4 + r;
#pragma unroll
      for (int db = 0; db < 4; ++db)
        yb[(size_t)rowq * (NH * HD) + h * HD + db * 16 + col] = f2bf(o[db][r] * inv);
    }
  };
  run_strip(127 - p);
  run_strip(p);
}

extern "C" void kernel_launch(void* const* d_in, const int* in_sizes, int n_in,
                              void* d_out, int out_size, void* d_ws, size_t ws_size,
                              hipStream_t stream) {
  (void)in_sizes; (void)n_in; (void)out_size; (void)ws_size;
  const float* x  = (const float*)d_in[0];
  const float* fc = (const float*)d_in[1];
  const float* fs = (const float*)d_in[2];
  const float* wq = (const float*)d_in[4];
  const float* wk = (const float*)d_in[5];
  const float* wv = (const float*)d_in[6];
  const float* wo = (const float*)d_in[7];
  ushort* w = (ushort*)d_ws;
  const size_t M1 = 1024 * 1024;
  ushort* xb    = w;
  ushort* wqkvb = w + 4 * M1;
  ushort* wob   = w + 10 * M1;
  ushort* qkvb  = w + 14 * M1;
  ushort* qb    = w + 20 * M1;
  ushort* kb    = w + 24 * M1;
  ushort* vt    = w + 25 * M1;
  ushort* yb    = w + 26 * M1;

  convert_all<<<14336, 256, 0, stream>>>(x, wq, wk, wv, wo, xb, wqkvb, wob);
  gemm_bt<1><<<dim3(QKVF / 128, S_LEN / 128), 256, 0, stream>>>(xb, wqkvb, qkvb, S_LEN, QKVF, DIMN);
  rope_layout<<<dim3(48, 8), 256, 0, stream>>>(qkvb, fc, fs, qb, kb, vt);
  attn<<<dim3(NH, 64), 64, 0, stream>>>(qb, kb, vt, yb);
  gemm_bt<0><<<dim3(DIMN / 128, S_LEN / 128), 256, 0, stream>>>(yb, wob, d_out, S_LEN, DIMN, NH * HD);
}

// Round 5
// 286.791 us; speedup vs baseline: 1.1850x; 1.1850x over previous
//
#include <hip/hip_runtime.h>

// Fused attention prefill, bf16 MFMA pipeline.
// ws layout (ushort units, 1M = 1024*1024):
//   xb 0..4M | wqkvb 4M..10M | wob 10M..14M | qkvb 14M..20M | qb 20M..24M
//   kb 24M..25M | vt 25M..26M | yb 26M..30M   => 60 MB total.

typedef __attribute__((ext_vector_type(8))) __bf16 bf16x8;
typedef __attribute__((ext_vector_type(4))) float f32x4;

#define S_LEN 2048
#define DIMN  2048
#define NH    32
#define NKV   8
#define HD    64
#define QKVF  3072

__device__ __forceinline__ ushort f2bf(float f) {
  union { float f; unsigned u; } v; v.f = f;
  unsigned r = v.u + 0x7fffu + ((v.u >> 16) & 1u);
  return (ushort)(r >> 16);
}
__device__ __forceinline__ unsigned pack_bf2_rz(float a, float b) {
  union { float f; unsigned u; } va, vb; va.f = a; vb.f = b;
  return (va.u >> 16) | (vb.u & 0xffff0000u);
}
__device__ __forceinline__ float bf2f(ushort u) {
  union { unsigned u; float f; } v; v.u = ((unsigned)u) << 16;
  return v.f;
}
__device__ __forceinline__ void gld_lds16(const void* g, void* l) {
  __builtin_amdgcn_global_load_lds(
      (const __attribute__((address_space(1))) unsigned int*)g,
      (__attribute__((address_space(3))) unsigned int*)l, 16, 0, 0);
}

// ---------------- f32 -> bf16 conversion (x, [wq;wk;wv], wo) ----------------
__global__ __launch_bounds__(256) void convert_all(
    const float* __restrict__ x, const float* __restrict__ wq,
    const float* __restrict__ wk, const float* __restrict__ wv,
    const float* __restrict__ wo, ushort* __restrict__ xb,
    ushort* __restrict__ wqkvb, ushort* __restrict__ wob) {
  const size_t NX = 4u * 1024 * 1024;
  const size_t NK = 1024 * 1024;
  size_t idx = ((size_t)blockIdx.x * 256 + threadIdx.x) * 4;
  const float* src; ushort* dst;
  if (idx < NX)                { src = x  + idx;                  dst = xb + idx; }
  else if (idx < 2 * NX)       { src = wq + (idx - NX);           dst = wqkvb + (idx - NX); }
  else if (idx < 2 * NX + NK)  { src = wk + (idx - 2 * NX);       dst = wqkvb + NX + (idx - 2 * NX); }
  else if (idx < 2 * NX + 2*NK){ src = wv + (idx - 2 * NX - NK);  dst = wqkvb + NX + NK + (idx - 2 * NX - NK); }
  else                         { src = wo + (idx - 2 * NX - 2*NK);dst = wob + (idx - 2 * NX - 2 * NK); }
  float4 v = *(const float4*)src;
  ushort4 o; o.x = f2bf(v.x); o.y = f2bf(v.y); o.z = f2bf(v.z); o.w = f2bf(v.w);
  *(ushort4*)dst = o;
}

// ---------------- GEMM (m97 structure): global_load_lds width-16, LDB=64 ----
template <int OUT_BF16>
__global__ __launch_bounds__(256) void gemm_bt(
    const ushort* __restrict__ A, const ushort* __restrict__ B,
    void* __restrict__ Cv, int M, int N, int K) {
  __shared__ __align__(16) ushort As[128 * 64];
  __shared__ __align__(16) ushort Bs[128 * 64];
  const int n0 = blockIdx.x * 128, m0 = blockIdx.y * 128;
  const int t = threadIdx.x;
  const int lane = t & 63, wave = t >> 6;
  const int wm = (wave >> 1) * 64, wn = (wave & 1) * 64;
  const int col = lane & 15, quad = lane >> 4;
  const int srow = wave * 32 + (lane >> 3);
  const int scol = (lane & 7) * 8;
  f32x4 acc[4][4] = {};
  for (int kk = 0; kk < K; kk += 64) {
    __syncthreads();
#pragma unroll
    for (int c = 0; c < 4; ++c) {
      int row = srow + c * 8;
      gld_lds16(&A[(size_t)(m0 + row) * K + kk + scol], &As[(wave * 32 + c * 8) * 64]);
      gld_lds16(&B[(size_t)(n0 + row) * K + kk + scol], &Bs[(wave * 32 + c * 8) * 64]);
    }
    __syncthreads();
#pragma unroll
    for (int kc = 0; kc < 64; kc += 32) {
      bf16x8 af[4], bfr[4];
#pragma unroll
      for (int i = 0; i < 4; ++i)
        af[i] = *(const bf16x8*)&As[(wm + i * 16 + col) * 64 + kc + quad * 8];
#pragma unroll
      for (int j = 0; j < 4; ++j)
        bfr[j] = *(const bf16x8*)&Bs[(wn + j * 16 + col) * 64 + kc + quad * 8];
#pragma unroll
      for (int i = 0; i < 4; ++i)
#pragma unroll
        for (int j = 0; j < 4; ++j)
          acc[i][j] = __builtin_amdgcn_mfma_f32_16x16x32_bf16(af[i], bfr[j], acc[i][j], 0, 0, 0);
    }
  }
#pragma unroll
  for (int i = 0; i < 4; ++i)
#pragma unroll
    for (int r = 0; r < 4; ++r) {
      int m = m0 + wm + i * 16 + quad * 4 + r;
      if (OUT_BF16) {
        ushort* C = (ushort*)Cv;
#pragma unroll
        for (int j = 0; j < 4; ++j)
          C[(size_t)m * N + n0 + wn + j * 16 + col] = f2bf(acc[i][j][r]);
      } else {
        float* C = (float*)Cv;
#pragma unroll
        for (int j = 0; j < 4; ++j)
          C[(size_t)m * N + n0 + wn + j * 16 + col] = acc[i][j][r];
      }
    }
}

// ---------------- RoPE + layout, coalesced ----------------------------------
// q is pre-scaled by (1/8)*log2(e) (folded softmax scale).
// vt stores keys permuted within each 64-tile: pos p holds key u=(p&3)*16+(p>>2)
// (matches attn's P-store permutation; PV result invariant).
__global__ __launch_bounds__(256) void rope_layout(
    const ushort* __restrict__ qkv, const float* __restrict__ fc,
    const float* __restrict__ fs, ushort* __restrict__ qb,
    ushort* __restrict__ kb, ushort* __restrict__ vt) {
  __shared__ ushort T[64][72];
  const int hh = blockIdx.x;
  const int s0 = blockIdx.y * 256;
  const int t = threadIdx.x;
  if (hh < 40) {
    const int srcoff = (hh < 32) ? hh * 64 : 2048 + (hh - 32) * 64;
    ushort* dst = (hh < 32) ? qb + (size_t)hh * S_LEN * 64
                            : kb + (size_t)(hh - 32) * S_LEN * 64;
    const float qs = (hh < 32) ? 0.18033688011112042f : 1.0f;
    const int sr = t >> 4, dc = (t & 15) * 4, i0 = (t & 15) * 2;
#pragma unroll 4
    for (int pass = 0; pass < 16; ++pass) {
      int s = s0 + pass * 16 + sr;
      ushort4 vv = *(const ushort4*)&qkv[(size_t)s * QKVF + srcoff + dc];
      float2 cc = *(const float2*)&fc[s * 32 + i0];
      float2 ss = *(const float2*)&fs[s * 32 + i0];
      float xr0 = bf2f(vv.x), xi0 = bf2f(vv.y), xr1 = bf2f(vv.z), xi1 = bf2f(vv.w);
      ushort4 ov;
      ov.x = f2bf((xr0 * cc.x - xi0 * ss.x) * qs); ov.y = f2bf((xr0 * ss.x + xi0 * cc.x) * qs);
      ov.z = f2bf((xr1 * cc.y - xi1 * ss.y) * qs); ov.w = f2bf((xr1 * ss.y + xi1 * cc.y) * qs);
      *(ushort4*)&dst[(size_t)s * 64 + dc] = ov;
    }
  } else {
    const int vh = hh - 40;
    for (int sub = 0; sub < 4; ++sub) {
      int sb = s0 + sub * 64;
      int sr = t >> 2, dc = (t & 3) * 16;
      ushort tmp[16];
      *(int4*)&tmp[0] = *(const int4*)&qkv[(size_t)(sb + sr) * QKVF + 2560 + vh * 64 + dc];
      *(int4*)&tmp[8] = *(const int4*)&qkv[(size_t)(sb + sr) * QKVF + 2560 + vh * 64 + dc + 8];
      __syncthreads();  // WAR vs previous sub's reads
      const int pcol = ((sr & 15) << 2) | (sr >> 4);  // permuted position
#pragma unroll
      for (int k = 0; k < 16; ++k) T[dc + k][pcol] = tmp[k];
      __syncthreads();
      int d = t >> 2, sc2 = (t & 3) * 16;
      int4 w0 = *(const int4*)&T[d][sc2];
      int4 w1 = *(const int4*)&T[d][sc2 + 8];
      *(int4*)&vt[((size_t)vh * 64 + d) * S_LEN + sb + sc2] = w0;
      *(int4*)&vt[((size_t)vh * 64 + d) * S_LEN + sb + sc2 + 8] = w1;
    }
  }
}

// ---------------- Flash attention v5: paired strips + K-split ---------------
// Block (h,p): strips sA=63-p, sB=p (32 rows each), 33 tiles combined.
// 2 waves split the tile ranges (16-17 tiles each); partial (O,l) merged via
// LDS (valid: max-free softmax => partials additive). One uniform barrier.
struct K8 { bf16x8 f[8]; };

__global__ __launch_bounds__(128, 2) void attn(
    const ushort* __restrict__ qbg, const ushort* __restrict__ kbg,
    const ushort* __restrict__ vtg, ushort* __restrict__ yb) {
  __shared__ __align__(16) ushort Ps[2][2][2][16][72];  // [wave][parity][ss]
  __shared__ __align__(16) float MB[2][64][40];         // [strip][lane][32 o + 8 l]
  const int h = blockIdx.x;
  const int p = blockIdx.y;
  const int kvh = h >> 2;
  const int wave = threadIdx.x >> 6;
  const int lane = threadIdx.x & 63;
  const int col = lane & 15, quad = lane >> 4;
  const ushort* qh = qbg + (size_t)h * S_LEN * HD;
  const ushort* kh = kbg + (size_t)kvh * S_LEN * HD;
  const ushort* vh = vtg + (size_t)kvh * HD * S_LEN;

  const int sA = 63 - p, sB = p;
  const int ntA = (sA >> 1) + 1, ntB = (sB >> 1) + 1;
  const int ah = (ntA + 1) >> 1, bh = ntB >> 1;

  f32x4 o[2][4];
  f32x4 l[2];

  auto run_chunk = [&](int sX, int tb, int te) {
#pragma unroll
    for (int ss = 0; ss < 2; ++ss) {
      l[ss] = (f32x4){0.f, 0.f, 0.f, 0.f};
#pragma unroll
      for (int db = 0; db < 4; ++db) o[ss][db] = (f32x4){0.f, 0.f, 0.f, 0.f};
    }
    if (tb >= te) return;
    const int q0 = sX * 32;
    const int lastT = sX >> 1;  // strip's masked (diagonal) tile index
    bf16x8 qf[2][2];
#pragma unroll
    for (int ss = 0; ss < 2; ++ss)
#pragma unroll
      for (int c = 0; c < 2; ++c)
        qf[ss][c] = *(const bf16x8*)&qh[(size_t)(q0 + ss * 16 + col) * HD + c * 32 + quad * 8];
    K8 kb0, kb1;
    auto loadK = [&](int t0, K8& k) {
#pragma unroll
      for (int j = 0; j < 4; ++j)
#pragma unroll
        for (int c = 0; c < 2; ++c)
          k.f[j * 2 + c] = *(const bf16x8*)&kh[(size_t)(t0 + j * 16 + col) * HD + c * 32 + quad * 8];
    };
    auto body = [&](int it, K8& cur, K8& nxt) {
      const int t0 = it * 64;
      const int pb = it & 1;
      f32x4 sc[2][4] = {};
#pragma unroll
      for (int j = 0; j < 4; ++j)
#pragma unroll
        for (int ss = 0; ss < 2; ++ss) {
          sc[ss][j] = __builtin_amdgcn_mfma_f32_16x16x32_bf16(qf[ss][0], cur.f[j * 2], sc[ss][j], 0, 0, 0);
          sc[ss][j] = __builtin_amdgcn_mfma_f32_16x16x32_bf16(qf[ss][1], cur.f[j * 2 + 1], sc[ss][j], 0, 0, 0);
        }
      if (it + 1 < te) loadK(t0 + 64, nxt);
      const bool masked = (it == lastT);
#pragma unroll
      for (int ss = 0; ss < 2; ++ss)
#pragma unroll
        for (int r = 0; r < 4; ++r) {
          const int rowq = q0 + ss * 16 + quad * 4 + r;
          float pr[4];
#pragma unroll
          for (int j = 0; j < 4; ++j) {
            float e = __builtin_amdgcn_exp2f(sc[ss][j][r]);
            if (masked) e = (t0 + j * 16 + col > rowq) ? 0.f : e;
            pr[j] = e;
          }
          l[ss][r] += (pr[0] + pr[1]) + (pr[2] + pr[3]);
          // permuted columns: keys j stored contiguously at col*4+j
          uint2 pk;
          pk.x = pack_bf2_rz(pr[0], pr[1]);
          pk.y = pack_bf2_rz(pr[2], pr[3]);
          *(uint2*)&Ps[wave][pb][ss][quad * 4 + r][col * 4] = pk;
        }
#pragma unroll
      for (int c = 0; c < 2; ++c) {
        bf16x8 vf[4];
#pragma unroll
        for (int db = 0; db < 4; ++db)
          vf[db] = *(const bf16x8*)&vh[(size_t)(db * 16 + col) * S_LEN + t0 + c * 32 + quad * 8];
#pragma unroll
        for (int ss = 0; ss < 2; ++ss) {
          bf16x8 pf = *(const bf16x8*)&Ps[wave][pb][ss][col][c * 32 + quad * 8];
#pragma unroll
          for (int db = 0; db < 4; ++db)
            o[ss][db] = __builtin_amdgcn_mfma_f32_16x16x32_bf16(pf, vf[db], o[ss][db], 0, 0, 0);
        }
      }
    };
    loadK(tb * 64, kb0);
    int it = tb;
    while (true) {
      body(it, kb0, kb1);
      if (++it == te) break;
      body(it, kb1, kb0);
      if (++it == te) break;
    }
  };

  auto dump = [&](int strip) {
#pragma unroll
    for (int ss = 0; ss < 2; ++ss) {
#pragma unroll
      for (int db = 0; db < 4; ++db)
        *(f32x4*)&MB[strip][lane][ss * 16 + db * 4] = o[ss][db];
      *(f32x4*)&MB[strip][lane][32 + ss * 4] = l[ss];
    }
  };
  auto merge = [&](int strip) {
#pragma unroll
    for (int ss = 0; ss < 2; ++ss) {
#pragma unroll
      for (int db = 0; db < 4; ++db)
        o[ss][db] += *(const f32x4*)&MB[strip][lane][ss * 16 + db * 4];
      l[ss] += *(const f32x4*)&MB[strip][lane][32 + ss * 4];
    }
  };

  // wave0: B-chunk (dump) then A-chunk (keep, finalize A)
  // wave1: A-chunk (dump) then B-chunk (keep, finalize B)
  const int s1 = wave ? sA : sB;
  const int t1b = wave ? ah : 0, t1e = wave ? ntA : bh;
  const int s2 = wave ? sB : sA;
  const int t2b = wave ? bh : 0, t2e = wave ? ntB : ah;
  const int dumpIdx = wave ? 0 : 1;

  run_chunk(s1, t1b, t1e);
  dump(dumpIdx);
  run_chunk(s2, t2b, t2e);
  __syncthreads();
  merge(dumpIdx ^ 1);

  const int q0 = s2 * 32;
#pragma unroll
  for (int ss = 0; ss < 2; ++ss)
#pragma unroll
    for (int r = 0; r < 4; ++r) {
      float ls = l[ss][r];
      ls += __shfl_xor(ls, 1);
      ls += __shfl_xor(ls, 2);
      ls += __shfl_xor(ls, 4);
      ls += __shfl_xor(ls, 8);
      float inv = 1.0f / ls;
      int rowq = q0 + ss * 16 + quad * 4 + r;
#pragma unroll
      for (int db = 0; db < 4; ++db)
        yb[(size_t)rowq * (NH * HD) + h * HD + db * 16 + col] = f2bf(o[ss][db][r] * inv);
    }
}

extern "C" void kernel_launch(void* const* d_in, const int* in_sizes, int n_in,
                              void* d_out, int out_size, void* d_ws, size_t ws_size,
                              hipStream_t stream) {
  (void)in_sizes; (void)n_in; (void)out_size; (void)ws_size;
  const float* x  = (const float*)d_in[0];
  const float* fc = (const float*)d_in[1];
  const float* fs = (const float*)d_in[2];
  const float* wq = (const float*)d_in[4];
  const float* wk = (const float*)d_in[5];
  const float* wv = (const float*)d_in[6];
  const float* wo = (const float*)d_in[7];
  ushort* w = (ushort*)d_ws;
  const size_t M1 = 1024 * 1024;
  ushort* xb    = w;
  ushort* wqkvb = w + 4 * M1;
  ushort* wob   = w + 10 * M1;
  ushort* qkvb  = w + 14 * M1;
  ushort* qb    = w + 20 * M1;
  ushort* kb    = w + 24 * M1;
  ushort* vt    = w + 25 * M1;
  ushort* yb    = w + 26 * M1;

  convert_all<<<14336, 256, 0, stream>>>(x, wq, wk, wv, wo, xb, wqkvb, wob);
  gemm_bt<1><<<dim3(QKVF / 128, S_LEN / 128), 256, 0, stream>>>(xb, wqkvb, qkvb, S_LEN, QKVF, DIMN);
  rope_layout<<<dim3(48, 8), 256, 0, stream>>>(qkvb, fc, fs, qb, kb, vt);
  attn<<<dim3(NH, 32), 128, 0, stream>>>(qb, kb, vt, yb);
  gemm_bt<0><<<dim3(DIMN / 128, S_LEN / 128), 256, 0, stream>>>(yb, wob, d_out, S_LEN, DIMN, NH * HD);
}